// Round 6
// baseline (107.891 us; speedup 1.0000x reference)
//
#include <hip/hip_runtime.h>
#include <hip/hip_bf16.h>

#define DD 128
#define NCLS 10
#define CHUNK 256
#define KSTEP 32
#define NIT (CHUNK / KSTEP)

typedef __attribute__((ext_vector_type(8))) short s16x8;
typedef __attribute__((ext_vector_type(4))) float f32x4;
typedef __attribute__((ext_vector_type(4))) unsigned int u32x4;
typedef __attribute__((ext_vector_type(4))) unsigned short u16x4;

union FU { unsigned u[4]; s16x8 v; };

__device__ inline unsigned short f2bf(float x) {
  union { float f; unsigned u; } c; c.f = x;
  unsigned u = c.u;
  u += 0x7fffu + ((u >> 16) & 1u);   // RNE to bf16
  return (unsigned short)(u >> 16);
}

// ---------------- K0: zero meta+scal (128 ints) and M (10*16384 f32) ----------------
__global__ void k_init(int* __restrict__ ws32, float* __restrict__ M) {
  int gid = blockIdx.x * 256 + threadIdx.x;    // 640 blocks x 256 = 163840
  M[gid] = 0.0f;
  if (gid < 128) ws32[gid] = 0;
}

// ---------------- K1: labels + histogram; LAST block computes prefix+cursors ----------------
// meta: [0..9]=counts [10..20]=chunkstart [32..41]=cursors [63]=done-counter
__global__ void k_label(const float* __restrict__ Pi, int N, int nbk,
                        unsigned char* __restrict__ label, int* __restrict__ meta) {
  __shared__ float pish[2560];
  __shared__ int h[NCLS];
  int t = threadIdx.x;
  if (t < NCLS) h[t] = 0;
  size_t base4 = (size_t)blockIdx.x * 640;       // in f32x4 units
  size_t tot4 = (size_t)N * NCLS / 4;
  {
    const f32x4* src = (const f32x4*)Pi;
    f32x4* dst = (f32x4*)pish;
    for (int i = t; i < 640; i += 256) {
      size_t gi = base4 + i;
      f32x4 z = {0.f, 0.f, 0.f, 0.f};
      dst[i] = (gi < tot4) ? src[gi] : z;
    }
  }
  __syncthreads();
  int n = blockIdx.x * 256 + t;
  if (n < N) {
    const float* p = &pish[t * NCLS];
    float best = p[0]; int bj = 0;
#pragma unroll
    for (int j = 1; j < NCLS; j++) { float v = p[j]; if (v > best) { best = v; bj = j; } }
    label[n] = (unsigned char)bj;
    atomicAdd(&h[bj], 1);
  }
  __syncthreads();
  if (t < NCLS) {
    atomicAdd(&meta[t], h[t]);
    __threadfence();                 // each adder drains its own atomic before done-count
  }
  __syncthreads();
  if (t == 0) {
    int done = atomicAdd(&meta[63], 1);
    if (done == nbk - 1) {           // last block: prefix over padded counts
      int cs = 0;
      meta[10] = 0;
#pragma unroll
      for (int j = 0; j < NCLS; j++) {
        int cnt = atomicAdd(&meta[j], 0);      // coherent read
        int cp = (cnt + CHUNK - 1) / CHUNK;
        meta[32 + j] = cs * CHUNK;             // cursor = padded offset
        cs += cp;
        meta[10 + j + 1] = cs;
      }
      __threadfence();
    }
  }
}

// ---------------- K2: counting sort -> perm; tail blocks fill pad gaps ----------------
__global__ void k_rank(const unsigned char* __restrict__ label, int N, int nb,
                       int* __restrict__ meta, int* __restrict__ perm) {
  int bb = blockIdx.x;
  int t = threadIdx.x;
  if (bb >= nb) {                              // pad-fill blocks (one per class)
    int j = bb - nb;
    int dstart = meta[10 + j] * CHUNK + meta[j];
    int dend = meta[11 + j] * CHUNK;
    int idx = dstart + t;
    if (idx < dend) perm[idx] = -1;
    return;
  }
  __shared__ int h[NCLS];
  __shared__ int base[NCLS];
  if (t < NCLS) h[t] = 0;
  __syncthreads();
  int n = bb * 256 + t;
  int lj = 0, lr = 0;
  bool act = (n < N);
  if (act) { lj = label[n]; lr = atomicAdd(&h[lj], 1); }
  __syncthreads();
  if (t < NCLS) base[t] = atomicAdd(&meta[32 + t], h[t]);
  __syncthreads();
  if (act) perm[base[lj] + lr] = n;
}

// ---------------- K3: gather syrk; raw barriers keep prefetch loads in flight ----------
__global__ __launch_bounds__(256, 2) void k_syrk(const float* __restrict__ Z,
                                                 const int* __restrict__ perm,
                                                 const int* __restrict__ meta,
                                                 float* __restrict__ M,
                                                 float* __restrict__ scal) {
  __shared__ int permsh[CHUNK];
  __shared__ __align__(16) char tilec[2][8448];
  __shared__ float tred[4];
  int b = blockIdx.x;
  int t = threadIdx.x;
  if (b >= meta[20]) return;
  permsh[t] = perm[(size_t)b * CHUNK + t];
  int l = t & 63, w = t >> 6;
  int g = l >> 4, m = l & 15;
  int d0 = (w >> 1) * 64, e0 = (w & 1) * 64;
  int sk2 = t >> 4, sq = t & 15;
  f32x4 acc[4][4] = {};
  __syncthreads();

  f32x4 A0[4], A1[4];     // two prefetch sets

  auto LOAD = [&](f32x4* R, int ks) {
    int ra = permsh[ks * KSTEP + 2 * sk2];
    int rb = permsh[ks * KSTEP + 2 * sk2 + 1];
    f32x4 z = {0.f, 0.f, 0.f, 0.f};
    R[0] = z; R[1] = z; R[2] = z; R[3] = z;
    if (ra >= 0) { const float* zp = Z + (size_t)ra * DD + sq * 4;
                   R[0] = *(const f32x4*)zp; R[1] = *(const f32x4*)(zp + 64); }
    if (rb >= 0) { const float* zp = Z + (size_t)rb * DD + sq * 4;
                   R[2] = *(const f32x4*)zp; R[3] = *(const f32x4*)(zp + 64); }
  };
  auto STORE = [&](const f32x4* R, int buf) {
    u32x4 u0, u1;
#pragma unroll
    for (int i = 0; i < 4; i++) {
      u0[i] = (unsigned)f2bf(R[0][i]) | ((unsigned)f2bf(R[2][i]) << 16);
      u1[i] = (unsigned)f2bf(R[1][i]) | ((unsigned)f2bf(R[3][i]) << 16);
    }
    char* tb = tilec[buf] + sk2 * 528 + sq * 16;
    *(u32x4*)tb = u0;
    *(u32x4*)(tb + 256) = u1;
  };
  auto COMPUTE = [&](int buf) {
    FU A[4], B[4];
    const char* fbase = tilec[buf] + g * (4 * 528) + m * 4;
#pragma unroll
    for (int dt = 0; dt < 4; dt++) {
      const char* p = fbase + (d0 + dt * 16) * 4;
      A[dt].u[0] = *(const unsigned*)(p);
      A[dt].u[1] = *(const unsigned*)(p + 528);
      A[dt].u[2] = *(const unsigned*)(p + 1056);
      A[dt].u[3] = *(const unsigned*)(p + 1584);
    }
    if (d0 != e0) {
#pragma unroll
      for (int et = 0; et < 4; et++) {
        const char* p = fbase + (e0 + et * 16) * 4;
        B[et].u[0] = *(const unsigned*)(p);
        B[et].u[1] = *(const unsigned*)(p + 528);
        B[et].u[2] = *(const unsigned*)(p + 1056);
        B[et].u[3] = *(const unsigned*)(p + 1584);
      }
    } else {
#pragma unroll
      for (int et = 0; et < 4; et++) B[et] = A[et];
    }
#pragma unroll
    for (int dt = 0; dt < 4; dt++)
#pragma unroll
      for (int et = 0; et < 4; et++)
        acc[dt][et] = __builtin_amdgcn_mfma_f32_16x16x32_bf16(A[dt].v, B[et].v, acc[dt][et], 0, 0, 0);
  };

  // raw barrier: drain LDS ops only; global prefetch loads stay in flight
#define SOFT_BARRIER() do { \
    __builtin_amdgcn_sched_barrier(0); \
    asm volatile("s_waitcnt lgkmcnt(0)" ::: "memory"); \
    __builtin_amdgcn_s_barrier(); \
    __builtin_amdgcn_sched_barrier(0); \
  } while (0)

  LOAD(A0, 0);
  LOAD(A1, 1);
  STORE(A0, 0);
  SOFT_BARRIER();
#pragma unroll
  for (int ks = 0; ks < NIT; ks++) {
    if (ks + 2 < NIT) {               // prefetch 2 ahead into the freed set
      if (ks & 1) LOAD(A1, ks + 2); else LOAD(A0, ks + 2);
    }
    COMPUTE(ks & 1);
    if (ks + 1 < NIT) {               // convert+store next tile into other buffer
      if (ks & 1) STORE(A0, (ks + 1) & 1); else STORE(A1, (ks + 1) & 1);
    }
    SOFT_BARRIER();
  }
#undef SOFT_BARRIER

  // class of this chunk
  int j = 0;
#pragma unroll
  for (int jj = 1; jj < NCLS; jj++) if (b >= meta[10 + jj]) j = jj;
  float* mj = M + (size_t)j * 16384;
  float trloc = 0.0f;
#pragma unroll
  for (int dt = 0; dt < 4; dt++)
#pragma unroll
    for (int et = 0; et < 4; et++)
#pragma unroll
      for (int r = 0; r < 4; r++) {
        int row = d0 + dt * 16 + g * 4 + r;
        int col = e0 + et * 16 + m;
        atomicAdd(&mj[row * 128 + col], acc[dt][et][r]);
        if (row == col) trloc += acc[dt][et][r];
      }
#pragma unroll
  for (int o = 32; o; o >>= 1) trloc += __shfl_down(trloc, o);
  if (l == 0) tred[w] = trloc;
  __syncthreads();
  if (t == 0) atomicAdd(&scal[0], tred[0] + tred[1] + tred[2] + tred[3]);
}

// ---------------- K4: makeE (+t1,t2) + colnorm + loss_reg, one launch ----------------
// b<64: E from Gram=sum_j M[j]; 64..73: colnorm; 74..713: reg tiles
__global__ __launch_bounds__(256) void k_makeE_cn_reg(const float* __restrict__ M,
                                                      const float* __restrict__ Us,
                                                      const int* __restrict__ meta,
                                                      float* __restrict__ scal,
                                                      float* __restrict__ E,
                                                      unsigned short* __restrict__ Ebf,
                                                      float cf, float nf) {
  __shared__ __align__(16) char pool[17024];
  int b = blockIdx.x, t = threadIdx.x;
  if (b < 64) {
    float* red = (float*)pool;
    int idx = b * 256 + t;
    float gsum = 0.0f;
#pragma unroll
    for (int j = 0; j < NCLS; j++) gsum += M[(size_t)j * 16384 + idx];
    float c = 1.0f + cf * scal[0] * (1.0f / 128.0f);
    float rc = 1.0f / c;
    int dg = ((idx >> 7) == (idx & 127)) ? 1 : 0;
    float e = (cf * rc) * gsum + (dg ? (rc - 1.0f) : 0.0f);
    E[idx] = e;
    Ebf[idx] = f2bf(e);
    float p1 = dg ? e : 0.0f;
    float p2 = e * e;
#pragma unroll
    for (int o = 32; o; o >>= 1) { p1 += __shfl_down(p1, o); p2 += __shfl_down(p2, o); }
    if ((t & 63) == 0) { red[t >> 6] = p1; red[4 + (t >> 6)] = p2; }
    __syncthreads();
    if (t == 0) {
      atomicAdd(&scal[3], red[0] + red[1] + red[2] + red[3]);
      atomicAdd(&scal[4], red[4] + red[5] + red[6] + red[7]);
    }
  } else if (b < 64 + NCLS) {
    int j = b - 64;
    const float* U = Us + (size_t)j * 16384;
    int e = t & 127, half = t >> 7;
    float* cs = (float*)pool;            // 128 floats
    float* red2 = (float*)(pool + 512);
    float acc = 0.0f;
    int d0 = half * 64;
    for (int d2 = d0; d2 < d0 + 64; d2++) { float v = U[d2 * 128 + e]; acc += v * v; }
    if (half == 0) cs[e] = acc;
    __syncthreads();
    float trj = (float)meta[j];
    float term = 0.0f;
    if (half == 1) {
      float tot = cs[e] + acc;
      term = log1pf((256.0f / trj) * tot);
    }
#pragma unroll
    for (int o = 32; o; o >>= 1) term += __shfl_down(term, o);
    if ((t & 63) == 0) red2[t >> 6] = term;
    __syncthreads();
    if (t == 0) atomicAdd(&scal[1], (trj / (2.0f * nf)) * (red2[2] + red2[3]));
  } else {
    int bid = b - 64 - NCLS;             // 640 = 10 * 64
    int j = bid >> 6, tile = bid & 63;
    int dr = (tile >> 3) << 4, er = (tile & 7) << 4;
    float (*ldsA)[132] = (float(*)[132])pool;
    float (*ldsB)[132] = (float(*)[132])(pool + 8448);
    float* wsum = (float*)(pool + 16896);
    int r = t >> 4, cb = t & 15;
    const float* src = Us + (size_t)j * 16384;
    {
      f32x4 a0 = *(const f32x4*)(src + (dr + r) * 128 + cb * 8);
      f32x4 a1 = *(const f32x4*)(src + (dr + r) * 128 + cb * 8 + 4);
      *(f32x4*)(&ldsA[r][cb * 8]) = a0;
      *(f32x4*)(&ldsA[r][cb * 8 + 4]) = a1;
      f32x4 b0 = *(const f32x4*)(src + (er + r) * 128 + cb * 8);
      f32x4 b1 = *(const f32x4*)(src + (er + r) * 128 + cb * 8 + 4);
      *(f32x4*)(&ldsB[r][cb * 8]) = b0;
      *(f32x4*)(&ldsB[r][cb * 8 + 4]) = b1;
    }
    __syncthreads();
    int dd = t >> 4, ee = t & 15;
    const f32x4* rA = (const f32x4*)(&ldsA[dd][0]);
    const f32x4* rB = (const f32x4*)(&ldsB[ee][0]);
    f32x4 s4 = {0.f, 0.f, 0.f, 0.f};
#pragma unroll
    for (int k4 = 0; k4 < 32; k4++) s4 += rA[k4] * rB[k4];
    float acc = s4[0] + s4[1] + s4[2] + s4[3];
    float mval = M[(size_t)j * 16384 + (dr + dd) * 128 + (er + ee)];
    float v = mval - acc;
    float sq = v * v;
#pragma unroll
    for (int o = 32; o; o >>= 1) sq += __shfl_down(sq, o);
    if ((t & 63) == 0) wsum[t >> 6] = sq;
    __syncthreads();
    if (t == 0) atomicAdd(&scal[2], wsum[0] + wsum[1] + wsum[2] + wsum[3]);
  }
}

// ---------------- K5: fused E2 + E3 traces + finalize, one block ----------------
__global__ __launch_bounds__(256) void k_e2e3_final(const unsigned short* __restrict__ Ebf,
                                                    const float* __restrict__ E,
                                                    const float* __restrict__ scal,
                                                    float* __restrict__ out, float cf) {
  __shared__ __align__(16) char ldsX[8448];
  __shared__ __align__(16) char ldsY[8448];
  __shared__ float red[4][4];
  int t = threadIdx.x;
  int l = t & 63, w = t >> 6;
  int g = l >> 4, m = l & 15;
  int d0 = (w >> 1) * 64, e0 = (w & 1) * 64;
  int sk2 = t >> 4, sq = t & 15;

  auto STAGE_X = [&](int ks) {      // Ebf rows ks*32..+31 -> ldsX paired layout
    int k0 = ks * 32 + 2 * sk2;
#pragma unroll
    for (int qi = 0; qi < 2; qi++) {
      int q = sq + qi * 16;
      u16x4 a = *(const u16x4*)(Ebf + k0 * 128 + q * 4);
      u16x4 bb = *(const u16x4*)(Ebf + (k0 + 1) * 128 + q * 4);
      u32x4 u;
#pragma unroll
      for (int i = 0; i < 4; i++) u[i] = (unsigned)a[i] | ((unsigned)bb[i] << 16);
      *(u32x4*)(ldsX + sk2 * 528 + q * 16) = u;
    }
  };
  auto FRAGS = [&](const char* lds, int c0, FU* F) {
    const char* fb = lds + g * (4 * 528) + m * 4;
#pragma unroll
    for (int ft = 0; ft < 4; ft++) {
      const char* p = fb + (c0 + ft * 16) * 4;
      F[ft].u[0] = *(const unsigned*)(p);
      F[ft].u[1] = *(const unsigned*)(p + 528);
      F[ft].u[2] = *(const unsigned*)(p + 1056);
      F[ft].u[3] = *(const unsigned*)(p + 1584);
    }
  };

  // ---- mm1: E2 = E^T E (E symmetric) ----
  f32x4 acc2[4][4] = {};
  for (int ks = 0; ks < 4; ks++) {
    __syncthreads();
    STAGE_X(ks);
    __syncthreads();
    FU A[4], B[4];
    FRAGS(ldsX, d0, A);
    if (e0 != d0) FRAGS(ldsX, e0, B);
    else { for (int i = 0; i < 4; i++) B[i] = A[i]; }
#pragma unroll
    for (int dt = 0; dt < 4; dt++)
#pragma unroll
      for (int et = 0; et < 4; et++)
        acc2[dt][et] = __builtin_amdgcn_mfma_f32_16x16x32_bf16(A[dt].v, B[et].v, acc2[dt][et], 0, 0, 0);
  }
  float t3 = 0.f, t4 = 0.f;
#pragma unroll
  for (int dt = 0; dt < 4; dt++)
#pragma unroll
    for (int et = 0; et < 4; et++)
#pragma unroll
      for (int r = 0; r < 4; r++) {
        int row = d0 + dt * 16 + g * 4 + r;
        int col = e0 + et * 16 + m;
        float p = acc2[dt][et][r];
        t3 += p * E[row * 128 + col];
        t4 += p * p;
      }

  // ---- mm2: E3 = E^T E2 ----
  f32x4 acc3[4][4] = {};
  for (int ks = 0; ks < 4; ks++) {
    __syncthreads();
    STAGE_X(ks);
    // owning waves write E2 rows ks*32..+31 into ldsY paired layout (from acc2 regs)
    int dsrc = (ks < 2) ? 0 : 64;
    if (d0 == dsrc) {
      int dtb = 2 * (ks & 1);
#pragma unroll
      for (int dd = 0; dd < 2; dd++) {
        int dt = dtb + dd;
#pragma unroll
        for (int et = 0; et < 4; et++)
#pragma unroll
          for (int r = 0; r < 4; r++) {
            int lrow = dd * 16 + g * 4 + r;            // 0..31 local row
            int col = e0 + et * 16 + m;
            unsigned short v = f2bf(acc2[dt][et][r]);
            *(unsigned short*)(ldsY + (lrow >> 1) * 528 + col * 4 + (lrow & 1) * 2) = v;
          }
      }
    }
    __syncthreads();
    FU A[4], B[4];
    FRAGS(ldsX, d0, A);
    FRAGS(ldsY, e0, B);
#pragma unroll
    for (int dt = 0; dt < 4; dt++)
#pragma unroll
      for (int et = 0; et < 4; et++)
        acc3[dt][et] = __builtin_amdgcn_mfma_f32_16x16x32_bf16(A[dt].v, B[et].v, acc3[dt][et], 0, 0, 0);
  }
  float t5 = 0.f, t6 = 0.f;
#pragma unroll
  for (int dt = 0; dt < 4; dt++)
#pragma unroll
    for (int et = 0; et < 4; et++)
#pragma unroll
      for (int r = 0; r < 4; r++) {
        float p = acc3[dt][et][r];
        t5 += p * acc2[dt][et][r];
        t6 += p * p;
      }

#pragma unroll
  for (int o = 32; o; o >>= 1) {
    t3 += __shfl_down(t3, o); t4 += __shfl_down(t4, o);
    t5 += __shfl_down(t5, o); t6 += __shfl_down(t6, o);
  }
  __syncthreads();
  if (l == 0) { red[w][0] = t3; red[w][1] = t4; red[w][2] = t5; red[w][3] = t6; }
  __syncthreads();
  if (t == 0) {
    float T3 = 0, T4 = 0, T5 = 0, T6 = 0;
#pragma unroll
    for (int i = 0; i < 4; i++) { T3 += red[i][0]; T4 += red[i][1]; T5 += red[i][2]; T6 += red[i][3]; }
    float c = 1.0f + cf * scal[0] * (1.0f / 128.0f);
    float t1 = scal[3], t2 = scal[4];
    float logdet = 128.0f * logf(c) + t1 - 0.5f * t2 + T3 * (1.0f / 3.0f)
                 - 0.25f * T4 + T5 * 0.2f - T6 * (1.0f / 6.0f);
    float R = 0.5f * logdet;
    float Rc = scal[1];
    float reg = 0.5f * scal[2];
    out[0] = -(R - Rc - reg);
    out[1] = R;
    out[2] = Rc;
    out[3] = reg;
  }
}

extern "C" void kernel_launch(void* const* d_in, const int* in_sizes, int n_in,
                              void* d_out, int out_size, void* d_ws, size_t ws_size,
                              hipStream_t stream) {
  const float* Z = (const float*)d_in[0];
  const float* Pi = (const float*)d_in[1];
  const float* Us = (const float*)d_in[2];
  float* out = (float*)d_out;
  int N = in_sizes[0] / DD;
  int NPAD = N + NCLS * CHUNK;
  int MC = (N + CHUNK - 1) / CHUNK + NCLS;
  float cf = (float)DD / ((float)N * 0.5f);   // d/(n*eps)

  char* ws = (char*)d_ws;
  int* meta = (int*)ws;                       // 64 ints
  float* scal = (float*)(ws + 256);           // 16 floats
  int* perm = (int*)(ws + 512);
  size_t off = 512 + (size_t)NPAD * 4;
  off = (off + 511) & ~511ull;
  unsigned char* label = (unsigned char*)(ws + off);
  off += (size_t)N; off = (off + 511) & ~511ull;
  float* M = (float*)(ws + off); off += (size_t)NCLS * 16384 * 4;
  float* E = (float*)(ws + off); off += (size_t)16384 * 4;
  unsigned short* Ebf = (unsigned short*)(ws + off); off += (size_t)16384 * 2;

  int nb = (N + 255) / 256;
  k_init<<<640, 256, 0, stream>>>((int*)ws, M);
  k_label<<<nb, 256, 0, stream>>>(Pi, N, nb, label, meta);
  k_rank<<<nb + NCLS, 256, 0, stream>>>(label, N, nb, meta, perm);
  k_syrk<<<MC, 256, 0, stream>>>(Z, perm, meta, M, scal);
  k_makeE_cn_reg<<<74 + 640, 256, 0, stream>>>(M, Us, meta, scal, E, Ebf, cf, (float)N);
  k_e2e3_final<<<1, 256, 0, stream>>>(Ebf, E, scal, out, cf);
}

// Round 7
// 107.357 us; speedup vs baseline: 1.0050x; 1.0050x over previous
//
#include <hip/hip_runtime.h>
#include <hip/hip_bf16.h>

#define DD 128
#define NCLS 10
#define CHUNK 512
#define KSTEP 32

typedef __attribute__((ext_vector_type(8))) short s16x8;
typedef __attribute__((ext_vector_type(4))) float f32x4;
typedef __attribute__((ext_vector_type(4))) unsigned int u32x4;
typedef __attribute__((ext_vector_type(8))) unsigned short u16x8;
typedef __attribute__((ext_vector_type(4))) unsigned short u16x4;

union FU { unsigned u[4]; s16x8 v; };

__device__ inline unsigned short f2bf(float x) {
  union { float f; unsigned u; } c; c.f = x;
  unsigned u = c.u;
  u += 0x7fffu + ((u >> 16) & 1u);   // RNE to bf16
  return (unsigned short)(u >> 16);
}

// frag fetch from paired [k2][col][2] LDS tile (verified layout, 528-B pair stride)
__device__ __forceinline__ void frags4(const char* lds, int g, int m, int c0, FU* F) {
  const char* fb = lds + g * (4 * 528) + m * 4;
#pragma unroll
  for (int ft = 0; ft < 4; ft++) {
    const char* p = fb + (c0 + ft * 16) * 4;
    F[ft].u[0] = *(const unsigned*)(p);
    F[ft].u[1] = *(const unsigned*)(p + 528);
    F[ft].u[2] = *(const unsigned*)(p + 1056);
    F[ft].u[3] = *(const unsigned*)(p + 1584);
  }
}

// ---------------- K0: zero meta + scal ----------------
__global__ void k_init(int* __restrict__ ws32) {
  ws32[threadIdx.x] = 0;     // 128 ints
}

// ---------------- K1: labels + histogram; LAST block computes prefix+cursors ----------
// meta: [0..9]=counts [10..20]=chunkstart [32..41]=row cursors [63]=done-counter
__global__ void k_label(const float* __restrict__ Pi, int N, int nbk,
                        unsigned char* __restrict__ label, int* __restrict__ meta) {
  __shared__ float pish[2560];
  __shared__ int h[NCLS];
  int t = threadIdx.x;
  if (t < NCLS) h[t] = 0;
  size_t base4 = (size_t)blockIdx.x * 640;
  size_t tot4 = (size_t)N * NCLS / 4;
  {
    const f32x4* src = (const f32x4*)Pi;
    f32x4* dst = (f32x4*)pish;
    for (int i = t; i < 640; i += 256) {
      size_t gi = base4 + i;
      f32x4 z = {0.f, 0.f, 0.f, 0.f};
      dst[i] = (gi < tot4) ? src[gi] : z;
    }
  }
  __syncthreads();
  int n = blockIdx.x * 256 + t;
  if (n < N) {
    const float* p = &pish[t * NCLS];
    float best = p[0]; int bj = 0;
#pragma unroll
    for (int j = 1; j < NCLS; j++) { float v = p[j]; if (v > best) { best = v; bj = j; } }
    label[n] = (unsigned char)bj;
    atomicAdd(&h[bj], 1);
  }
  __syncthreads();
  if (t < NCLS) {
    atomicAdd(&meta[t], h[t]);
    __threadfence();
  }
  __syncthreads();
  if (t == 0) {
    int done = atomicAdd(&meta[63], 1);
    if (done == nbk - 1) {
      int cs = 0;
      meta[10] = 0;
#pragma unroll
      for (int j = 0; j < NCLS; j++) {
        int cnt = atomicAdd(&meta[j], 0);
        int cp = (cnt + CHUNK - 1) / CHUNK;
        meta[32 + j] = cs * CHUNK;            // row cursor base
        cs += cp;
        meta[10 + j + 1] = cs;
      }
      __threadfence();
    }
  }
}

// ---------------- K2: pack (class-sorted bf16 copy) + padzero + UUt/colnorm --------
// blocks [0,nb): stream 256 rows, LDS bucket by class, coalesced scatter-append
// blocks [nb, nb+10): zero pad rows of class j
// blocks [nb+10, nb+20): UUt_j = U_j U_j^T via MFMA, + ||UUt||^2 -> scal[2], colnorm -> scal[1]
__global__ __launch_bounds__(256) void k_pack(const float* __restrict__ Z,
                                              const float* __restrict__ Us,
                                              const unsigned char* __restrict__ label,
                                              int* __restrict__ meta,
                                              float* __restrict__ scal,
                                              unsigned short* __restrict__ packed,
                                              float* __restrict__ UUt,
                                              float nf, int nb) {
  __shared__ __align__(16) char pool[69632];          // 256 rows x 272 B
  __shared__ int h[NCLS], loff[NCLS], gbase[NCLS];
  __shared__ short sortedIdx[256];
  __shared__ int slotArr[256];
  __shared__ float fred[8];
  int b = blockIdx.x, t = threadIdx.x;

  if (b < nb) {
    // ---- phase 1: coalesced read Z -> bf16 rows in LDS (stride 272) ----
    size_t n0 = (size_t)b * 256;
    const f32x4* Z4 = (const f32x4*)Z;
#pragma unroll 4
    for (int pass = 0; pass < 32; pass++) {
      int il = pass * 256 + t;
      int row = il >> 5, qq = il & 31;
      f32x4 v = Z4[(n0 + row) * 32 + qq];
      unsigned lo = (unsigned)f2bf(v[0]) | ((unsigned)f2bf(v[1]) << 16);
      unsigned hi = (unsigned)f2bf(v[2]) | ((unsigned)f2bf(v[3]) << 16);
      *(uint2*)(pool + row * 272 + qq * 8) = make_uint2(lo, hi);
    }
    // ---- phase 2: local counting sort + global slot allocation ----
    if (t < NCLS) h[t] = 0;
    __syncthreads();
    int myj = label[n0 + t];
    int myr = atomicAdd(&h[myj], 1);
    __syncthreads();
    if (t == 0) {
      int c = 0;
#pragma unroll
      for (int j = 0; j < NCLS; j++) { loff[j] = c; c += h[j]; }
    }
    __syncthreads();
    if (t < NCLS) gbase[t] = atomicAdd(&meta[32 + t], h[t]);
    __syncthreads();
    int lpos = loff[myj] + myr;
    sortedIdx[lpos] = (short)t;
    slotArr[lpos] = gbase[myj] + myr;
    __syncthreads();
    // ---- phase 3: coalesced class-run writes ----
#pragma unroll
    for (int pass = 0; pass < 16; pass++) {
      int lidx = pass * 16 + (t >> 4);
      int q = t & 15;
      int src = sortedIdx[lidx];
      size_t slot = (size_t)slotArr[lidx];
      u32x4 val = *(const u32x4*)(pool + src * 272 + q * 16);
      *(u32x4*)((char*)packed + slot * 256 + q * 16) = val;
    }
  } else if (b < nb + NCLS) {
    // ---- pad rows -> zero ----
    int j = b - nb;
    int dstart = meta[10 + j] * CHUNK + meta[j];
    int dend = meta[11 + j] * CHUNK;
    int nrows = dend - dstart;
    u32x4 z = {0u, 0u, 0u, 0u};
    for (int i = t; i < nrows * 16; i += 256)
      *(u32x4*)((char*)packed + (size_t)dstart * 256 + (size_t)i * 16) = z;
  } else {
    // ---- UUt_j + ||UUt||^2 + colnorm ----
    int j = b - nb - NCLS;
    const float* U = Us + (size_t)j * 16384;
    // colnorm (round-6 verified logic)
    {
      float* cs = (float*)(pool + 8448);
      float* red2 = (float*)(pool + 8960);
      int e = t & 127, half = t >> 7;
      float acc = 0.0f;
      int dd0 = half * 64;
      for (int d2 = dd0; d2 < dd0 + 64; d2++) { float v = U[d2 * 128 + e]; acc += v * v; }
      if (half == 0) cs[e] = acc;
      __syncthreads();
      float trj = (float)meta[j];
      float term = 0.0f;
      if (half == 1) {
        float tot = cs[e] + acc;
        term = log1pf((256.0f / trj) * tot);
      }
#pragma unroll
      for (int o = 32; o; o >>= 1) term += __shfl_down(term, o);
      if ((t & 63) == 0) red2[t >> 6] = term;
      __syncthreads();
      if (t == 0) atomicAdd(&scal[1], (trj / (2.0f * nf)) * (red2[2] + red2[3]));
    }
    __syncthreads();
    // UUt via MFMA: Gram over U's column index (stage transposed, paired)
    char* ldsY = pool;
    int l = t & 63, w = t >> 6;
    int g = l >> 4, m = l & 15;
    int d0 = (w >> 1) * 64, e0 = (w & 1) * 64;
    int sk2 = t >> 4, q = t & 15;
    f32x4 acc[4][4] = {};
    for (int ks = 0; ks < 4; ks++) {
      int k0 = ks * 32;
      __syncthreads();
      unsigned wv[8];
#pragma unroll
      for (int i = 0; i < 8; i++) {
        int c = 8 * q + i;
        wv[i] = (unsigned)f2bf(U[c * 128 + k0 + 2 * sk2])
              | ((unsigned)f2bf(U[c * 128 + k0 + 2 * sk2 + 1]) << 16);
      }
      u32x4 w0 = {wv[0], wv[1], wv[2], wv[3]};
      u32x4 w1 = {wv[4], wv[5], wv[6], wv[7]};
      *(u32x4*)(ldsY + sk2 * 528 + q * 32) = w0;
      *(u32x4*)(ldsY + sk2 * 528 + q * 32 + 16) = w1;
      __syncthreads();
      FU A[4], B[4];
      frags4(ldsY, g, m, d0, A);
      if (e0 != d0) frags4(ldsY, g, m, e0, B);
      else { for (int i = 0; i < 4; i++) B[i] = A[i]; }
#pragma unroll
      for (int dt = 0; dt < 4; dt++)
#pragma unroll
        for (int et = 0; et < 4; et++)
          acc[dt][et] = __builtin_amdgcn_mfma_f32_16x16x32_bf16(A[dt].v, B[et].v, acc[dt][et], 0, 0, 0);
    }
    float* uo = UUt + (size_t)j * 16384;
    float sq = 0.f;
#pragma unroll
    for (int dt = 0; dt < 4; dt++)
#pragma unroll
      for (int et = 0; et < 4; et++)
#pragma unroll
        for (int r = 0; r < 4; r++) {
          int row = d0 + dt * 16 + g * 4 + r;
          int col = e0 + et * 16 + m;
          float p = acc[dt][et][r];
          uo[row * 128 + col] = p;
          sq += p * p;
        }
#pragma unroll
    for (int o = 32; o; o >>= 1) sq += __shfl_down(sq, o);
    if (l == 0) fred[w] = sq;
    __syncthreads();
    if (t == 0) atomicAdd(&scal[2], fred[0] + fred[1] + fred[2] + fred[3]);
  }
}

// ---------------- K3: dense coalesced syrk over packed chunks ----------------
__global__ __launch_bounds__(256, 2) void k_syrk(const unsigned short* __restrict__ packed,
                                                 const int* __restrict__ meta,
                                                 const float* __restrict__ UUt,
                                                 float* __restrict__ partial,
                                                 float* __restrict__ scal) {
  __shared__ __align__(16) char tilec[2][8448];
  __shared__ float tred[8];
  int b = blockIdx.x, t = threadIdx.x;
  if (b >= meta[20]) return;
  int l = t & 63, w = t >> 6;
  int g = l >> 4, m = l & 15;
  int d0 = (w >> 1) * 64, e0 = (w & 1) * 64;
  int sk2 = t >> 4, q = t & 15;
  size_t rowbase = (size_t)b * CHUNK;
  f32x4 acc[4][4] = {};

  auto PACKW = [&](const u16x8& a, const u16x8& bb, int buf) {
    unsigned wv[8];
#pragma unroll
    for (int i = 0; i < 8; i++)
      wv[i] = (unsigned)(unsigned short)a[i] | ((unsigned)(unsigned short)bb[i] << 16);
    u32x4 w0 = {wv[0], wv[1], wv[2], wv[3]};
    u32x4 w1 = {wv[4], wv[5], wv[6], wv[7]};
    char* tb = tilec[buf] + sk2 * 528 + q * 32;
    *(u32x4*)tb = w0;
    *(u32x4*)(tb + 16) = w1;
  };
  auto COMPUTE = [&](int buf) {
    FU A[4], B[4];
    frags4(tilec[buf], g, m, d0, A);
    if (d0 != e0) frags4(tilec[buf], g, m, e0, B);
    else { for (int i = 0; i < 4; i++) B[i] = A[i]; }
#pragma unroll
    for (int dt = 0; dt < 4; dt++)
#pragma unroll
      for (int et = 0; et < 4; et++)
        acc[dt][et] = __builtin_amdgcn_mfma_f32_16x16x32_bf16(A[dt].v, B[et].v, acc[dt][et], 0, 0, 0);
  };

  {
    const unsigned short* src = packed + rowbase * DD;
    u16x8 a = *(const u16x8*)(src + (2 * sk2) * DD + q * 8);
    u16x8 bb = *(const u16x8*)(src + (2 * sk2 + 1) * DD + q * 8);
    PACKW(a, bb, 0);
  }
  __syncthreads();
  for (int ks = 0; ks < CHUNK / KSTEP; ks++) {
    u16x8 na, nb2;
    bool more = (ks + 1 < CHUNK / KSTEP);
    if (more) {
      const unsigned short* src = packed + (rowbase + (size_t)(ks + 1) * KSTEP) * DD;
      na = *(const u16x8*)(src + (2 * sk2) * DD + q * 8);
      nb2 = *(const u16x8*)(src + (2 * sk2 + 1) * DD + q * 8);
    }
    COMPUTE(ks & 1);
    __syncthreads();
    if (more) PACKW(na, nb2, (ks + 1) & 1);
    __syncthreads();
  }

  int j = 0;
#pragma unroll
  for (int jj = 1; jj < NCLS; jj++) if (b >= meta[10 + jj]) j = jj;
  float* pb = partial + (size_t)b * 16384;
  const float* uu = UUt + (size_t)j * 16384;
  float trloc = 0.0f, dot = 0.0f;
#pragma unroll
  for (int dt = 0; dt < 4; dt++)
#pragma unroll
    for (int et = 0; et < 4; et++)
#pragma unroll
      for (int r = 0; r < 4; r++) {
        int row = d0 + dt * 16 + g * 4 + r;
        int col = e0 + et * 16 + m;
        float p = acc[dt][et][r];
        pb[row * 128 + col] = p;
        dot += p * uu[row * 128 + col];
        if (row == col) trloc += p;
      }
#pragma unroll
  for (int o = 32; o; o >>= 1) { trloc += __shfl_down(trloc, o); dot += __shfl_down(dot, o); }
  if (l == 0) { tred[w] = trloc; tred[4 + w] = dot; }
  __syncthreads();
  if (t == 0) {
    atomicAdd(&scal[0], tred[0] + tred[1] + tred[2] + tred[3]);
    atomicAdd(&scal[2], -2.0f * (tred[4] + tred[5] + tred[6] + tred[7]));
  }
}

// ---------------- K4: reduce partials -> Gram, ||M||^2, E, Ebf, t1, t2 ----------------
__global__ void k_reduceE(const float* __restrict__ partial, const int* __restrict__ meta,
                          float* __restrict__ scal, float* __restrict__ E,
                          unsigned short* __restrict__ Ebf, float cf) {
  __shared__ float red[12];
  int t = threadIdx.x;
  int idx = blockIdx.x * 256 + t;     // 64 blocks
  float gsum = 0.f, sqs = 0.f;
#pragma unroll
  for (int j = 0; j < NCLS; j++) {
    int c0 = meta[10 + j], c1 = meta[11 + j];
    float s = 0.f;
#pragma unroll 4
    for (int c = c0; c < c1; c++) s += partial[(size_t)c * 16384 + idx];
    gsum += s; sqs += s * s;
  }
  float c = 1.0f + cf * scal[0] * (1.0f / 128.0f);
  float rc = 1.0f / c;
  int dg = ((idx >> 7) == (idx & 127)) ? 1 : 0;
  float e = (cf * rc) * gsum + (dg ? (rc - 1.0f) : 0.0f);
  E[idx] = e;
  Ebf[idx] = f2bf(e);
  float p1 = dg ? e : 0.0f;
  float p2 = e * e;
#pragma unroll
  for (int o = 32; o; o >>= 1) {
    p1 += __shfl_down(p1, o); p2 += __shfl_down(p2, o); sqs += __shfl_down(sqs, o);
  }
  if ((t & 63) == 0) { int wv = t >> 6; red[wv] = p1; red[4 + wv] = p2; red[8 + wv] = sqs; }
  __syncthreads();
  if (t == 0) {
    atomicAdd(&scal[3], red[0] + red[1] + red[2] + red[3]);
    atomicAdd(&scal[4], red[4] + red[5] + red[6] + red[7]);
    atomicAdd(&scal[2], red[8] + red[9] + red[10] + red[11]);
  }
}

// ---------------- K5: fused E2 + E3 traces + finalize, one block ----------------
__global__ __launch_bounds__(256) void k_final(const unsigned short* __restrict__ Ebf,
                                               const float* __restrict__ E,
                                               const float* __restrict__ scal,
                                               float* __restrict__ out, float cf) {
  __shared__ __align__(16) char ldsX[8448];
  __shared__ __align__(16) char ldsY[8448];
  __shared__ float red[4][4];
  int t = threadIdx.x;
  int l = t & 63, w = t >> 6;
  int g = l >> 4, m = l & 15;
  int d0 = (w >> 1) * 64, e0 = (w & 1) * 64;
  int sk2 = t >> 4, sq = t & 15;

  auto STAGE_X = [&](int ks) {
    int k0 = ks * 32 + 2 * sk2;
#pragma unroll
    for (int qi = 0; qi < 2; qi++) {
      int q = sq + qi * 16;
      u16x4 a = *(const u16x4*)(Ebf + k0 * 128 + q * 4);
      u16x4 bb = *(const u16x4*)(Ebf + (k0 + 1) * 128 + q * 4);
      u32x4 u;
#pragma unroll
      for (int i = 0; i < 4; i++) u[i] = (unsigned)a[i] | ((unsigned)bb[i] << 16);
      *(u32x4*)(ldsX + sk2 * 528 + q * 16) = u;
    }
  };

  // ---- mm1: E2 = E^T E ----
  f32x4 acc2[4][4] = {};
  for (int ks = 0; ks < 4; ks++) {
    __syncthreads();
    STAGE_X(ks);
    __syncthreads();
    FU A[4], B[4];
    frags4(ldsX, g, m, d0, A);
    if (e0 != d0) frags4(ldsX, g, m, e0, B);
    else { for (int i = 0; i < 4; i++) B[i] = A[i]; }
#pragma unroll
    for (int dt = 0; dt < 4; dt++)
#pragma unroll
      for (int et = 0; et < 4; et++)
        acc2[dt][et] = __builtin_amdgcn_mfma_f32_16x16x32_bf16(A[dt].v, B[et].v, acc2[dt][et], 0, 0, 0);
  }
  float t3 = 0.f, t4 = 0.f;
#pragma unroll
  for (int dt = 0; dt < 4; dt++)
#pragma unroll
    for (int et = 0; et < 4; et++)
#pragma unroll
      for (int r = 0; r < 4; r++) {
        int row = d0 + dt * 16 + g * 4 + r;
        int col = e0 + et * 16 + m;
        float p = acc2[dt][et][r];
        t3 += p * E[row * 128 + col];
        t4 += p * p;
      }

  // ---- mm2: E3 = E^T E2 ----
  f32x4 acc3[4][4] = {};
  for (int ks = 0; ks < 4; ks++) {
    __syncthreads();
    STAGE_X(ks);
    int dsrc = (ks < 2) ? 0 : 64;
    if (d0 == dsrc) {
      int dtb = 2 * (ks & 1);
#pragma unroll
      for (int dd = 0; dd < 2; dd++) {
        int dt = dtb + dd;
#pragma unroll
        for (int et = 0; et < 4; et++)
#pragma unroll
          for (int r = 0; r < 4; r++) {
            int lrow = dd * 16 + g * 4 + r;
            int col = e0 + et * 16 + m;
            unsigned short v = f2bf(acc2[dt][et][r]);
            *(unsigned short*)(ldsY + (lrow >> 1) * 528 + col * 4 + (lrow & 1) * 2) = v;
          }
      }
    }
    __syncthreads();
    FU A[4], B[4];
    frags4(ldsX, g, m, d0, A);
    frags4(ldsY, g, m, e0, B);
#pragma unroll
    for (int dt = 0; dt < 4; dt++)
#pragma unroll
      for (int et = 0; et < 4; et++)
        acc3[dt][et] = __builtin_amdgcn_mfma_f32_16x16x32_bf16(A[dt].v, B[et].v, acc3[dt][et], 0, 0, 0);
  }
  float t5 = 0.f, t6 = 0.f;
#pragma unroll
  for (int dt = 0; dt < 4; dt++)
#pragma unroll
    for (int et = 0; et < 4; et++)
#pragma unroll
      for (int r = 0; r < 4; r++) {
        float p = acc3[dt][et][r];
        t5 += p * acc2[dt][et][r];
        t6 += p * p;
      }

#pragma unroll
  for (int o = 32; o; o >>= 1) {
    t3 += __shfl_down(t3, o); t4 += __shfl_down(t4, o);
    t5 += __shfl_down(t5, o); t6 += __shfl_down(t6, o);
  }
  __syncthreads();
  if (l == 0) { red[w][0] = t3; red[w][1] = t4; red[w][2] = t5; red[w][3] = t6; }
  __syncthreads();
  if (t == 0) {
    float T3 = 0, T4 = 0, T5 = 0, T6 = 0;
#pragma unroll
    for (int i = 0; i < 4; i++) { T3 += red[i][0]; T4 += red[i][1]; T5 += red[i][2]; T6 += red[i][3]; }
    float c = 1.0f + cf * scal[0] * (1.0f / 128.0f);
    float t1 = scal[3], t2 = scal[4];
    float logdet = 128.0f * logf(c) + t1 - 0.5f * t2 + T3 * (1.0f / 3.0f)
                 - 0.25f * T4 + T5 * 0.2f - T6 * (1.0f / 6.0f);
    float R = 0.5f * logdet;
    float Rc = scal[1];
    float reg = 0.5f * scal[2];
    out[0] = -(R - Rc - reg);
    out[1] = R;
    out[2] = Rc;
    out[3] = reg;
  }
}

extern "C" void kernel_launch(void* const* d_in, const int* in_sizes, int n_in,
                              void* d_out, int out_size, void* d_ws, size_t ws_size,
                              hipStream_t stream) {
  const float* Z = (const float*)d_in[0];
  const float* Pi = (const float*)d_in[1];
  const float* Us = (const float*)d_in[2];
  float* out = (float*)d_out;
  int N = in_sizes[0] / DD;
  int MC = (N + CHUNK - 1) / CHUNK + NCLS;          // max chunks
  int NPROWS = MC * CHUNK;
  float cf = (float)DD / ((float)N * 0.5f);         // d/(n*eps)

  char* ws = (char*)d_ws;
  int* meta = (int*)ws;                              // 64 ints
  float* scal = (float*)(ws + 256);                  // 16 floats
  size_t off = 512;
  unsigned char* label = (unsigned char*)(ws + off);
  off += (size_t)N; off = (off + 511) & ~511ull;
  unsigned short* packed = (unsigned short*)(ws + off); off += (size_t)NPROWS * DD * 2;
  off = (off + 511) & ~511ull;
  float* UUt = (float*)(ws + off); off += (size_t)NCLS * 16384 * 4;
  float* E = (float*)(ws + off); off += (size_t)16384 * 4;
  unsigned short* Ebf = (unsigned short*)(ws + off); off += (size_t)16384 * 2;
  off = (off + 511) & ~511ull;
  float* partial = (float*)(ws + off); off += (size_t)MC * 16384 * 4;

  int nb = (N + 255) / 256;
  k_init<<<1, 128, 0, stream>>>((int*)ws);
  k_label<<<nb, 256, 0, stream>>>(Pi, N, nb, label, meta);
  k_pack<<<nb + 2 * NCLS, 256, 0, stream>>>(Z, Us, label, meta, scal, packed, UUt, (float)N, nb);
  k_syrk<<<MC, 256, 0, stream>>>(packed, meta, UUt, partial, scal);
  k_reduceE<<<64, 256, 0, stream>>>(partial, meta, scal, E, Ebf, cf);
  k_final<<<1, 256, 0, stream>>>(Ebf, E, scal, out, cf);
}